// Round 1
// baseline (70568.549 us; speedup 1.0000x reference)
//
#include <hip/hip_runtime.h>
#include <math.h>

// Problem constants (match reference)
#define Hn   2560      // hidden units
#define Bn   64        // batch
#define INW  128       // input width
#define ETOT 2048      // total excitatory units (4 areas x 512)

__device__ __forceinline__ int area_of(int h) {
  return h < ETOT ? (h >> 9) : ((h - ETOT) >> 7);
}

// ---------------------------------------------------------------------------
// Prep 1: WT[k][h] = sign(k) * |Wrec[h][k]| * conn(h,k), diag removed.
// 64x64 LDS tile transpose. grid (40,40), block (64,16).
// ---------------------------------------------------------------------------
__global__ void build_wrecT(const float* __restrict__ Wrec, float* __restrict__ WT) {
  __shared__ float tile[64][65];
  int h0 = blockIdx.x * 64;
  int k0 = blockIdx.y * 64;
  int tx = threadIdx.x;   // 0..63
  int ty = threadIdx.y;   // 0..15
  #pragma unroll
  for (int j = 0; j < 64; j += 16)
    tile[ty + j][tx] = Wrec[(size_t)(h0 + ty + j) * Hn + k0 + tx];
  __syncthreads();
  #pragma unroll
  for (int j = 0; j < 64; j += 16) {
    int k = k0 + ty + j;   // out row (source unit)
    int h = h0 + tx;       // out col (target unit), lane-minor -> coalesced
    float v = fabsf(tile[tx][ty + j]);
    int ah = area_of(h);
    int conn;
    float sgn;
    if (k < ETOT) { int ak = k >> 9; int d = ah - ak; conn = (d <= 1 && d >= -1); sgn = 1.f; }
    else          { int ak = (k - ETOT) >> 7; conn = (ah == ak); sgn = -1.f; }
    if (h == k) conn = 0;
    WT[(size_t)k * Hn + h] = conn ? sgn * v : 0.f;
  }
}

// ---------------------------------------------------------------------------
// Prep 2: WinT[i][h] = |Win[h][i]| * (area(h)==0). grid (40,2), block (64,16).
// ---------------------------------------------------------------------------
__global__ void build_winT(const float* __restrict__ Win, float* __restrict__ WinT) {
  __shared__ float tile[64][65];
  int h0 = blockIdx.x * 64;
  int i0 = blockIdx.y * 64;
  int tx = threadIdx.x, ty = threadIdx.y;
  #pragma unroll
  for (int j = 0; j < 64; j += 16)
    tile[ty + j][tx] = Win[(size_t)(h0 + ty + j) * INW + i0 + tx];
  __syncthreads();
  #pragma unroll
  for (int j = 0; j < 64; j += 16) {
    int i = i0 + ty + j;
    int h = h0 + tx;
    float v = fabsf(tile[tx][ty + j]);
    WinT[(size_t)i * Hn + h] = (area_of(h) == 0) ? v : 0.f;
  }
}

// ---------------------------------------------------------------------------
// Prep 3: inpT[t][i][b] = inputs[t][b][i]. One block per t, 256 threads.
// ---------------------------------------------------------------------------
__global__ void build_inpT(const float* __restrict__ inp, float* __restrict__ inpT) {
  __shared__ float tile[64 * 129];   // +1 pad per row -> no bank conflicts
  int t = blockIdx.x;
  const float* src = inp + (size_t)t * Bn * INW;
  float* dst = inpT + (size_t)t * INW * Bn;
  for (int idx = threadIdx.x; idx < Bn * INW; idx += blockDim.x) {
    int b = idx >> 7, i = idx & 127;
    tile[b * 129 + i] = src[idx];
  }
  __syncthreads();
  for (int idx = threadIdx.x; idx < Bn * INW; idx += blockDim.x) {
    int i = idx >> 6, b = idx & 63;
    dst[idx] = tile[b * 129 + i];
  }
}

// ---------------------------------------------------------------------------
// Per-timestep kernel. grid 640 x 64 threads (1 wave per block).
// Wave tile: 16 h (lane-minor, coalesced WT loads) x 16 b (4 b-lanes x float4).
// Masked ranges are block-uniform (16-h groups never straddle a segment).
// r kept transposed rT[h][b] (ping-pong); x transposed xT[h][b].
// ---------------------------------------------------------------------------
__global__ __launch_bounds__(64) void rnn_step(
    const float* __restrict__ WT, const float* __restrict__ WinT,
    const float* __restrict__ inpT, const float* __restrict__ inp,
    const float* __restrict__ brec,
    const float* __restrict__ rsrc, float* __restrict__ rdst,
    float* __restrict__ xT, float* __restrict__ rates,
    int t, int useInpT)
{
  int bid = blockIdx.x;
  int hg = bid % 160;          // 160 h-groups of 16
  int bg = bid / 160;          // 4 b-groups of 16
  int lane = threadIdx.x;
  int hi = lane & 15, bj = lane >> 4;
  int h = hg * 16 + hi;
  int b0 = bg * 16 + bj * 4;

  int a = area_of(h);
  int kE0 = (a == 0 ? 0 : a - 1) << 9;
  int kE1 = ((a == 3 ? 3 : a + 1) + 1) << 9;
  int kI0 = ETOT + (a << 7);

  float acc0 = 0.f, acc1 = 0.f, acc2 = 0.f, acc3 = 0.f;
  const float* rs = rsrc + b0;

  #pragma unroll 4
  for (int k = kE0; k < kE1; ++k) {
    float w = WT[(size_t)k * Hn + h];
    float4 r4 = *(const float4*)(rs + (size_t)k * Bn);
    acc0 = fmaf(w, r4.x, acc0);
    acc1 = fmaf(w, r4.y, acc1);
    acc2 = fmaf(w, r4.z, acc2);
    acc3 = fmaf(w, r4.w, acc3);
  }
  #pragma unroll 4
  for (int k = kI0; k < kI0 + 128; ++k) {
    float w = WT[(size_t)k * Hn + h];
    float4 r4 = *(const float4*)(rs + (size_t)k * Bn);
    acc0 = fmaf(w, r4.x, acc0);
    acc1 = fmaf(w, r4.y, acc1);
    acc2 = fmaf(w, r4.z, acc2);
    acc3 = fmaf(w, r4.w, acc3);
  }

  if (a == 0) {   // only area 0 receives external input (block-uniform branch)
    if (useInpT) {
      const float* ip = inpT + (size_t)t * INW * Bn + b0;
      #pragma unroll 4
      for (int i = 0; i < INW; ++i) {
        float w = WinT[(size_t)i * Hn + h];
        float4 u4 = *(const float4*)(ip + (size_t)i * Bn);
        acc0 = fmaf(w, u4.x, acc0);
        acc1 = fmaf(w, u4.y, acc1);
        acc2 = fmaf(w, u4.z, acc2);
        acc3 = fmaf(w, u4.w, acc3);
      }
    } else {
      const float* ip = inp + (size_t)t * Bn * INW;
      for (int i = 0; i < INW; ++i) {
        float w = WinT[(size_t)i * Hn + h];
        acc0 = fmaf(w, ip[(b0 + 0) * INW + i], acc0);
        acc1 = fmaf(w, ip[(b0 + 1) * INW + i], acc1);
        acc2 = fmaf(w, ip[(b0 + 2) * INW + i], acc2);
        acc3 = fmaf(w, ip[(b0 + 3) * INW + i], acc3);
      }
    }
  }

  float bb = brec[h];
  acc0 += bb; acc1 += bb; acc2 += bb; acc3 += bb;

  // leaky integration: x = 0.8*x + 0.2*pre   (ALPHA_X = DT/TAU_X = 0.2)
  float4 x4 = *(float4*)(xT + (size_t)h * Bn + b0);
  x4.x = 0.8f * x4.x + 0.2f * acc0;
  x4.y = 0.8f * x4.y + 0.2f * acc1;
  x4.z = 0.8f * x4.z + 0.2f * acc2;
  x4.w = 0.8f * x4.w + 0.2f * acc3;
  *(float4*)(xT + (size_t)h * Bn + b0) = x4;

  float r0 = tanhf(fmaxf(x4.x, 0.f));
  float r1 = tanhf(fmaxf(x4.y, 0.f));
  float r2 = tanhf(fmaxf(x4.z, 0.f));
  float r3 = tanhf(fmaxf(x4.w, 0.f));

  float4 ro = make_float4(r0, r1, r2, r3);
  *(float4*)(rdst + (size_t)h * Bn + b0) = ro;

  float* rt = rates + (size_t)t * Bn * Hn;
  rt[(size_t)(b0 + 0) * Hn + h] = r0;
  rt[(size_t)(b0 + 1) * Hn + h] = r1;
  rt[(size_t)(b0 + 2) * Hn + h] = r2;
  rt[(size_t)(b0 + 3) * Hn + h] = r3;
}

// ---------------------------------------------------------------------------
extern "C" void kernel_launch(void* const* d_in, const int* in_sizes, int n_in,
                              void* d_out, int out_size, void* d_ws, size_t ws_size,
                              hipStream_t stream) {
  const float* inputs = (const float*)d_in[0];   // [T, 64, 128]
  const float* Wrec   = (const float*)d_in[1];   // [2560, 2560]
  const float* brec   = (const float*)d_in[2];   // [2560]
  const float* Win    = (const float*)d_in[3];   // [2560, 128]
  int T = in_sizes[0] / (Bn * INW);              // 500

  float* ws = (float*)d_ws;
  size_t off = 0;
  float* WT   = ws + off; off += (size_t)Hn * Hn;    // 6.55M
  float* WinT = ws + off; off += (size_t)INW * Hn;   // 0.33M
  float* xT   = ws + off; off += (size_t)Hn * Bn;    // 0.16M
  float* rA   = ws + off; off += (size_t)Hn * Bn;
  float* rB   = ws + off; off += (size_t)Hn * Bn;
  float* inpT = ws + off;
  size_t needInpT = (off + (size_t)T * INW * Bn) * sizeof(float);
  int useInpT = (ws_size >= needInpT) ? 1 : 0;

  // x0 = 0, r0 = retanh(0) = 0  (ws is poisoned 0xAA before every call)
  hipMemsetAsync(xT, 0, (size_t)Hn * Bn * sizeof(float), stream);
  hipMemsetAsync(rA, 0, (size_t)Hn * Bn * sizeof(float), stream);

  build_wrecT<<<dim3(40, 40), dim3(64, 16), 0, stream>>>(Wrec, WT);
  build_winT<<<dim3(40, 2), dim3(64, 16), 0, stream>>>(Win, WinT);
  if (useInpT) build_inpT<<<T, 256, 0, stream>>>(inputs, inpT);

  float* rates = (float*)d_out;
  for (int t = 0; t < T; ++t) {
    const float* rs = (t & 1) ? rB : rA;
    float*       rd = (t & 1) ? rA : rB;
    rnn_step<<<640, 64, 0, stream>>>(WT, WinT, inpT, inputs, brec,
                                     rs, rd, xT, rates, t, useInpT);
  }
}

// Round 2
// 65433.032 us; speedup vs baseline: 1.0785x; 1.0785x over previous
//
#include <hip/hip_runtime.h>
#include <math.h>

// Problem constants (match reference)
#define Hn   2560      // hidden units
#define Bn   64        // batch
#define INW  128       // input width
#define ETOT 2048      // total excitatory units (4 areas x 512)
#define HGn  160       // h-groups of 16
#define MAXC 13        // max chunks per h-group

__device__ __forceinline__ int area_of(int h) {
  return h < ETOT ? (h >> 9) : ((h - ETOT) >> 7);
}

// ---------------------------------------------------------------------------
// Prep 1: WT[k][h] = sign(k) * |Wrec[h][k]| * conn(h,k), diag removed.
// ---------------------------------------------------------------------------
__global__ void build_wrecT(const float* __restrict__ Wrec, float* __restrict__ WT) {
  __shared__ float tile[64][65];
  int h0 = blockIdx.x * 64;
  int k0 = blockIdx.y * 64;
  int tx = threadIdx.x;   // 0..63
  int ty = threadIdx.y;   // 0..15
  #pragma unroll
  for (int j = 0; j < 64; j += 16)
    tile[ty + j][tx] = Wrec[(size_t)(h0 + ty + j) * Hn + k0 + tx];
  __syncthreads();
  #pragma unroll
  for (int j = 0; j < 64; j += 16) {
    int k = k0 + ty + j;   // out row (source unit)
    int h = h0 + tx;       // out col (target unit), lane-minor -> coalesced
    float v = fabsf(tile[tx][ty + j]);
    int ah = area_of(h);
    int conn;
    float sgn;
    if (k < ETOT) { int ak = k >> 9; int d = ah - ak; conn = (d <= 1 && d >= -1); sgn = 1.f; }
    else          { int ak = (k - ETOT) >> 7; conn = (ah == ak); sgn = -1.f; }
    if (h == k) conn = 0;
    WT[(size_t)k * Hn + h] = conn ? sgn * v : 0.f;
  }
}

// ---------------------------------------------------------------------------
// Prep 2: WinT[i][h] = |Win[h][i]| * (area(h)==0). Row stride Hn (same as WT).
// ---------------------------------------------------------------------------
__global__ void build_winT(const float* __restrict__ Win, float* __restrict__ WinT) {
  __shared__ float tile[64][65];
  int h0 = blockIdx.x * 64;
  int i0 = blockIdx.y * 64;
  int tx = threadIdx.x, ty = threadIdx.y;
  #pragma unroll
  for (int j = 0; j < 64; j += 16)
    tile[ty + j][tx] = Win[(size_t)(h0 + ty + j) * INW + i0 + tx];
  __syncthreads();
  #pragma unroll
  for (int j = 0; j < 64; j += 16) {
    int i = i0 + ty + j;
    int h = h0 + tx;
    float v = fabsf(tile[tx][ty + j]);
    WinT[(size_t)i * Hn + h] = (area_of(h) == 0) ? v : 0.f;
  }
}

// ---------------------------------------------------------------------------
// Prep 3: inpT[t][i][b] = inputs[t][b][i].
// ---------------------------------------------------------------------------
__global__ void build_inpT(const float* __restrict__ inp, float* __restrict__ inpT) {
  __shared__ float tile[64 * 129];
  int t = blockIdx.x;
  const float* src = inp + (size_t)t * Bn * INW;
  float* dst = inpT + (size_t)t * INW * Bn;
  for (int idx = threadIdx.x; idx < Bn * INW; idx += blockDim.x) {
    int b = idx >> 7, i = idx & 127;
    tile[b * 129 + i] = src[idx];
  }
  __syncthreads();
  for (int idx = threadIdx.x; idx < Bn * INW; idx += blockDim.x) {
    int i = idx >> 6, b = idx & 63;
    dst[idx] = tile[b * 129 + i];
  }
}

// ---------------------------------------------------------------------------
// Per-timestep kernel. Grid = 1800 single-wave blocks.
// Wave tile: 16 h x 64 b x 128 k. lane = batch -> r coalesced, w wave-uniform.
// Chunk map per 16-h group (area a): E chunks (8 or 12) + 1 I chunk
// (+ 1 input chunk for area 0). All chunks exactly 128 k, identical code.
// Split-k reduced via global partials + per-group counter + spin-finish.
// All 1800 waves are co-resident (<=128 VGPR, 0 LDS, 64-thr blocks).
// ---------------------------------------------------------------------------
__global__ __launch_bounds__(64, 4) void rnn_step(
    const float* __restrict__ WT, const float* __restrict__ WinT,
    const float* __restrict__ inpT, const float* __restrict__ inp,
    const float* __restrict__ brec,
    const float* __restrict__ rsrc, float* __restrict__ rdst,
    float* __restrict__ xT, float* __restrict__ rates,
    float* __restrict__ part, int* __restrict__ cnt,
    int t, int useInpT)
{
  int bid = blockIdx.x;
  int lane = threadIdx.x;

  // bid -> (h-group, chunk id, num chunks)
  int hg, c, nch;
  if (bid < 320)       { hg = bid / 10;                     c = bid - hg * 10;          nch = 10; }
  else if (bid < 1152) { int r = bid - 320;  hg = 32 + r / 13;  c = r - (hg - 32) * 13;  nch = 13; }
  else if (bid < 1440) { int r = bid - 1152; hg = 96 + r / 9;   c = r - (hg - 96) * 9;   nch = 9;  }
  else if (bid < 1520) { int r = bid - 1440; hg = 128 + r / 10; c = r - (hg - 128) * 10; nch = 10; }
  else if (bid < 1728) { int r = bid - 1520; hg = 136 + r / 13; c = r - (hg - 136) * 13; nch = 13; }
  else                 { int r = bid - 1728; hg = 152 + r / 9;  c = r - (hg - 152) * 9;  nch = 9;  }

  int h0 = hg * 16;
  int a  = (hg < 128) ? (hg >> 5) : ((hg - 128) >> 3);
  int nE = (a == 0 || a == 3) ? 8 : 12;
  int kE0 = (a == 0 ? 0 : (a - 1)) * 512;

  const float* wp;          // 16 consecutive floats per k-row, row stride Hn
  const float* rp;          // [128][64] operand rows, stride 64
  bool rawInput = false;
  if (c < nE)       { int k0 = kE0 + (c << 7);  wp = WT + (size_t)k0 * Hn + h0; rp = rsrc + ((size_t)k0 << 6); }
  else if (c == nE) { int k0 = ETOT + (a << 7); wp = WT + (size_t)k0 * Hn + h0; rp = rsrc + ((size_t)k0 << 6); }
  else {            // input-projection chunk (only area 0): W=WinT, r=inputs[t]
    wp = WinT + h0;
    if (useInpT) rp = inpT + (size_t)t * (INW * Bn);
    else { rp = inp + (size_t)t * (Bn * INW); rawInput = true; }
  }

  float acc[16];
  #pragma unroll
  for (int i = 0; i < 16; ++i) acc[i] = 0.f;

  if (!rawInput) {
    #pragma unroll 4
    for (int k = 0; k < 128; ++k) {
      const float4* wq = (const float4*)(wp + (size_t)k * Hn);  // wave-uniform
      float4 w0 = wq[0], w1 = wq[1], w2 = wq[2], w3 = wq[3];
      float rv = rp[(k << 6) + lane];                           // coalesced
      acc[ 0] = fmaf(w0.x, rv, acc[ 0]);  acc[ 1] = fmaf(w0.y, rv, acc[ 1]);
      acc[ 2] = fmaf(w0.z, rv, acc[ 2]);  acc[ 3] = fmaf(w0.w, rv, acc[ 3]);
      acc[ 4] = fmaf(w1.x, rv, acc[ 4]);  acc[ 5] = fmaf(w1.y, rv, acc[ 5]);
      acc[ 6] = fmaf(w1.z, rv, acc[ 6]);  acc[ 7] = fmaf(w1.w, rv, acc[ 7]);
      acc[ 8] = fmaf(w2.x, rv, acc[ 8]);  acc[ 9] = fmaf(w2.y, rv, acc[ 9]);
      acc[10] = fmaf(w2.z, rv, acc[10]);  acc[11] = fmaf(w2.w, rv, acc[11]);
      acc[12] = fmaf(w3.x, rv, acc[12]);  acc[13] = fmaf(w3.y, rv, acc[13]);
      acc[14] = fmaf(w3.z, rv, acc[14]);  acc[15] = fmaf(w3.w, rv, acc[15]);
    }
  } else {
    // fallback: read raw inputs [b][i] (per-lane row walk, L1-cached lines)
    #pragma unroll 4
    for (int k = 0; k < 128; ++k) {
      const float4* wq = (const float4*)(wp + (size_t)k * Hn);
      float4 w0 = wq[0], w1 = wq[1], w2 = wq[2], w3 = wq[3];
      float rv = rp[lane * INW + k];
      acc[ 0] = fmaf(w0.x, rv, acc[ 0]);  acc[ 1] = fmaf(w0.y, rv, acc[ 1]);
      acc[ 2] = fmaf(w0.z, rv, acc[ 2]);  acc[ 3] = fmaf(w0.w, rv, acc[ 3]);
      acc[ 4] = fmaf(w1.x, rv, acc[ 4]);  acc[ 5] = fmaf(w1.y, rv, acc[ 5]);
      acc[ 6] = fmaf(w1.z, rv, acc[ 6]);  acc[ 7] = fmaf(w1.w, rv, acc[ 7]);
      acc[ 8] = fmaf(w2.x, rv, acc[ 8]);  acc[ 9] = fmaf(w2.y, rv, acc[ 9]);
      acc[10] = fmaf(w2.z, rv, acc[10]);  acc[11] = fmaf(w2.w, rv, acc[11]);
      acc[12] = fmaf(w3.x, rv, acc[12]);  acc[13] = fmaf(w3.y, rv, acc[13]);
      acc[14] = fmaf(w3.z, rv, acc[14]);  acc[15] = fmaf(w3.w, rv, acc[15]);
    }
  }

  // store partials (coalesced 256 B per h-row)
  float* pb = part + ((size_t)(hg * MAXC + c) * 16) * 64 + lane;
  #pragma unroll
  for (int h = 0; h < 16; ++h) pb[h * 64] = acc[h];

  // release: partials visible before arrival tick
  __threadfence();
  int* cp = cnt + t * HGn + hg;
  if (lane == 0) __hip_atomic_fetch_add(cp, 1, __ATOMIC_RELEASE, __HIP_MEMORY_SCOPE_AGENT);

  // spin until all chunks of this h-group arrived (all waves co-resident)
  while (__hip_atomic_load(cp, __ATOMIC_ACQUIRE, __HIP_MEMORY_SCOPE_AGENT) < nch)
    __builtin_amdgcn_s_sleep(4);

  // cooperative finish: wave c owns h rows c, c+nch, ...
  for (int h = c; h < 16; h += nch) {
    float sum = 0.f;
    for (int cc = 0; cc < nch; ++cc)
      sum += part[((size_t)(hg * MAXC + cc) * 16 + h) * 64 + lane];
    float pre = sum + brec[h0 + h];
    size_t xi = (size_t)(h0 + h) * 64 + lane;
    float x = xT[xi];
    x = 0.8f * x + 0.2f * pre;          // ALPHA_X = 0.2
    xT[xi] = x;
    float rr = tanhf(fmaxf(x, 0.f));
    rdst[xi] = rr;
    rates[(size_t)t * (Bn * Hn) + (size_t)lane * Hn + h0 + h] = rr;
  }
}

// ---------------------------------------------------------------------------
extern "C" void kernel_launch(void* const* d_in, const int* in_sizes, int n_in,
                              void* d_out, int out_size, void* d_ws, size_t ws_size,
                              hipStream_t stream) {
  const float* inputs = (const float*)d_in[0];   // [T, 64, 128]
  const float* Wrec   = (const float*)d_in[1];   // [2560, 2560]
  const float* brec   = (const float*)d_in[2];   // [2560]
  const float* Win    = (const float*)d_in[3];   // [2560, 128]
  int T = in_sizes[0] / (Bn * INW);              // 500

  float* ws = (float*)d_ws;
  size_t off = 0;
  float* WT   = ws + off; off += (size_t)Hn * Hn;          // 6.55M
  float* WinT = ws + off; off += (size_t)INW * Hn;         // 0.33M
  float* xT   = ws + off; off += (size_t)Hn * Bn;
  float* rA   = ws + off; off += (size_t)Hn * Bn;
  float* rB   = ws + off; off += (size_t)Hn * Bn;
  float* part = ws + off; off += (size_t)HGn * MAXC * 16 * 64;   // 2.13M
  int*  cnt   = (int*)(ws + off); off += (size_t)T * HGn;        // 80K ints
  float* inpT = ws + off;
  size_t needInpT = (off + (size_t)T * INW * Bn) * sizeof(float);
  int useInpT = (ws_size >= needInpT) ? 1 : 0;

  // x0 = 0, r0 = retanh(0) = 0; counters = 0 (ws poisoned 0xAA each call)
  hipMemsetAsync(xT, 0, (size_t)Hn * Bn * sizeof(float), stream);
  hipMemsetAsync(rA, 0, (size_t)Hn * Bn * sizeof(float), stream);
  hipMemsetAsync(cnt, 0, (size_t)T * HGn * sizeof(int), stream);

  build_wrecT<<<dim3(40, 40), dim3(64, 16), 0, stream>>>(Wrec, WT);
  build_winT<<<dim3(40, 2), dim3(64, 16), 0, stream>>>(Win, WinT);
  if (useInpT) build_inpT<<<T, 256, 0, stream>>>(inputs, inpT);

  float* rates = (float*)d_out;
  for (int t = 0; t < T; ++t) {
    const float* rs = (t & 1) ? rB : rA;
    float*       rd = (t & 1) ? rA : rB;
    rnn_step<<<1800, 64, 0, stream>>>(WT, WinT, inpT, inputs, brec,
                                      rs, rd, xT, rates, part, cnt, t, useInpT);
  }
}

// Round 3
// 14263.518 us; speedup vs baseline: 4.9475x; 4.5874x over previous
//
#include <hip/hip_runtime.h>
#include <math.h>

// Problem constants (match reference)
#define Hn   2560      // hidden units
#define Bn   64        // batch
#define INW  128       // input width
#define ETOT 2048      // total excitatory units (4 areas x 512)
#define HGn  160       // h-groups of 16
#define MAXC 13        // max chunks per h-group

__device__ __forceinline__ int area_of(int h) {
  return h < ETOT ? (h >> 9) : ((h - ETOT) >> 7);
}

// ---------------------------------------------------------------------------
// Prep 1: WT[k][h] = sign(k) * |Wrec[h][k]| * conn(h,k), diag removed.
// ---------------------------------------------------------------------------
__global__ void build_wrecT(const float* __restrict__ Wrec, float* __restrict__ WT) {
  __shared__ float tile[64][65];
  int h0 = blockIdx.x * 64;
  int k0 = blockIdx.y * 64;
  int tx = threadIdx.x;   // 0..63
  int ty = threadIdx.y;   // 0..15
  #pragma unroll
  for (int j = 0; j < 64; j += 16)
    tile[ty + j][tx] = Wrec[(size_t)(h0 + ty + j) * Hn + k0 + tx];
  __syncthreads();
  #pragma unroll
  for (int j = 0; j < 64; j += 16) {
    int k = k0 + ty + j;   // out row (source unit)
    int h = h0 + tx;       // out col (target unit), lane-minor -> coalesced
    float v = fabsf(tile[tx][ty + j]);
    int ah = area_of(h);
    int conn;
    float sgn;
    if (k < ETOT) { int ak = k >> 9; int d = ah - ak; conn = (d <= 1 && d >= -1); sgn = 1.f; }
    else          { int ak = (k - ETOT) >> 7; conn = (ah == ak); sgn = -1.f; }
    if (h == k) conn = 0;
    WT[(size_t)k * Hn + h] = conn ? sgn * v : 0.f;
  }
}

// ---------------------------------------------------------------------------
// Prep 2: WinT[i][h] = |Win[h][i]| * (area(h)==0). Row stride Hn (same as WT).
// ---------------------------------------------------------------------------
__global__ void build_winT(const float* __restrict__ Win, float* __restrict__ WinT) {
  __shared__ float tile[64][65];
  int h0 = blockIdx.x * 64;
  int i0 = blockIdx.y * 64;
  int tx = threadIdx.x, ty = threadIdx.y;
  #pragma unroll
  for (int j = 0; j < 64; j += 16)
    tile[ty + j][tx] = Win[(size_t)(h0 + ty + j) * INW + i0 + tx];
  __syncthreads();
  #pragma unroll
  for (int j = 0; j < 64; j += 16) {
    int i = i0 + ty + j;
    int h = h0 + tx;
    float v = fabsf(tile[tx][ty + j]);
    WinT[(size_t)i * Hn + h] = (area_of(h) == 0) ? v : 0.f;
  }
}

// ---------------------------------------------------------------------------
// Prep 3: inpT[t][i][b] = inputs[t][b][i].
// ---------------------------------------------------------------------------
__global__ void build_inpT(const float* __restrict__ inp, float* __restrict__ inpT) {
  __shared__ float tile[64 * 129];
  int t = blockIdx.x;
  const float* src = inp + (size_t)t * Bn * INW;
  float* dst = inpT + (size_t)t * INW * Bn;
  for (int idx = threadIdx.x; idx < Bn * INW; idx += blockDim.x) {
    int b = idx >> 7, i = idx & 127;
    tile[b * 129 + i] = src[idx];
  }
  __syncthreads();
  for (int idx = threadIdx.x; idx < Bn * INW; idx += blockDim.x) {
    int i = idx >> 6, b = idx & 63;
    dst[idx] = tile[b * 129 + i];
  }
}

// ---------------------------------------------------------------------------
// Kernel A (per step): masked GEMM partials. Grid = 1800 single-wave blocks.
// Wave tile: 16 h x 64 b x 128 k. lane = batch -> r coalesced, w wave-uniform.
// NO atomics / fences / spins — partials become visible to kernel B through
// the implicit end-of-dispatch release (HW L2 flush per dispatch).
// ---------------------------------------------------------------------------
__global__ __launch_bounds__(64) void rnn_mm(
    const float* __restrict__ WT, const float* __restrict__ WinT,
    const float* __restrict__ inpT, const float* __restrict__ inp,
    const float* __restrict__ rsrc, float* __restrict__ part,
    int t, int useInpT)
{
  int bid = blockIdx.x;
  int lane = threadIdx.x;

  // bid -> (h-group, chunk id)
  int hg, c;
  if (bid < 320)       { hg = bid / 10;                      c = bid - hg * 10;          }
  else if (bid < 1152) { int r = bid - 320;  hg = 32 + r / 13;  c = r - (hg - 32) * 13;  }
  else if (bid < 1440) { int r = bid - 1152; hg = 96 + r / 9;   c = r - (hg - 96) * 9;   }
  else if (bid < 1520) { int r = bid - 1440; hg = 128 + r / 10; c = r - (hg - 128) * 10; }
  else if (bid < 1728) { int r = bid - 1520; hg = 136 + r / 13; c = r - (hg - 136) * 13; }
  else                 { int r = bid - 1728; hg = 152 + r / 9;  c = r - (hg - 152) * 9;  }

  int h0 = hg * 16;
  int a  = (hg < 128) ? (hg >> 5) : ((hg - 128) >> 3);
  int nE = (a == 0 || a == 3) ? 8 : 12;
  int kE0 = (a == 0 ? 0 : (a - 1)) * 512;

  const float* wp;          // 16 consecutive floats per k-row, row stride Hn
  const float* rp;          // [128][64] operand rows, stride 64
  bool rawInput = false;
  if (c < nE)       { int k0 = kE0 + (c << 7);  wp = WT + (size_t)k0 * Hn + h0; rp = rsrc + ((size_t)k0 << 6); }
  else if (c == nE) { int k0 = ETOT + (a << 7); wp = WT + (size_t)k0 * Hn + h0; rp = rsrc + ((size_t)k0 << 6); }
  else {            // input-projection chunk (only area 0): W=WinT, r=inputs[t]
    wp = WinT + h0;
    if (useInpT) rp = inpT + (size_t)t * (INW * Bn);
    else { rp = inp + (size_t)t * (Bn * INW); rawInput = true; }
  }

  float acc[16];
  #pragma unroll
  for (int i = 0; i < 16; ++i) acc[i] = 0.f;

  if (!rawInput) {
    #pragma unroll 4
    for (int k = 0; k < 128; ++k) {
      const float4* wq = (const float4*)(wp + (size_t)k * Hn);  // wave-uniform
      float4 w0 = wq[0], w1 = wq[1], w2 = wq[2], w3 = wq[3];
      float rv = rp[(k << 6) + lane];                           // coalesced
      acc[ 0] = fmaf(w0.x, rv, acc[ 0]);  acc[ 1] = fmaf(w0.y, rv, acc[ 1]);
      acc[ 2] = fmaf(w0.z, rv, acc[ 2]);  acc[ 3] = fmaf(w0.w, rv, acc[ 3]);
      acc[ 4] = fmaf(w1.x, rv, acc[ 4]);  acc[ 5] = fmaf(w1.y, rv, acc[ 5]);
      acc[ 6] = fmaf(w1.z, rv, acc[ 6]);  acc[ 7] = fmaf(w1.w, rv, acc[ 7]);
      acc[ 8] = fmaf(w2.x, rv, acc[ 8]);  acc[ 9] = fmaf(w2.y, rv, acc[ 9]);
      acc[10] = fmaf(w2.z, rv, acc[10]);  acc[11] = fmaf(w2.w, rv, acc[11]);
      acc[12] = fmaf(w3.x, rv, acc[12]);  acc[13] = fmaf(w3.y, rv, acc[13]);
      acc[14] = fmaf(w3.z, rv, acc[14]);  acc[15] = fmaf(w3.w, rv, acc[15]);
    }
  } else {
    #pragma unroll 4
    for (int k = 0; k < 128; ++k) {
      const float4* wq = (const float4*)(wp + (size_t)k * Hn);
      float4 w0 = wq[0], w1 = wq[1], w2 = wq[2], w3 = wq[3];
      float rv = rp[lane * INW + k];
      acc[ 0] = fmaf(w0.x, rv, acc[ 0]);  acc[ 1] = fmaf(w0.y, rv, acc[ 1]);
      acc[ 2] = fmaf(w0.z, rv, acc[ 2]);  acc[ 3] = fmaf(w0.w, rv, acc[ 3]);
      acc[ 4] = fmaf(w1.x, rv, acc[ 4]);  acc[ 5] = fmaf(w1.y, rv, acc[ 5]);
      acc[ 6] = fmaf(w1.z, rv, acc[ 6]);  acc[ 7] = fmaf(w1.w, rv, acc[ 7]);
      acc[ 8] = fmaf(w2.x, rv, acc[ 8]);  acc[ 9] = fmaf(w2.y, rv, acc[ 9]);
      acc[10] = fmaf(w2.z, rv, acc[10]);  acc[11] = fmaf(w2.w, rv, acc[11]);
      acc[12] = fmaf(w3.x, rv, acc[12]);  acc[13] = fmaf(w3.y, rv, acc[13]);
      acc[14] = fmaf(w3.z, rv, acc[14]);  acc[15] = fmaf(w3.w, rv, acc[15]);
    }
  }

  // store partials (coalesced 256 B per h-row)
  float* pb = part + ((size_t)(hg * MAXC + c) * 16) * 64 + lane;
  #pragma unroll
  for (int h = 0; h < 16; ++h) pb[h * 64] = acc[h];
}

// ---------------------------------------------------------------------------
// Kernel B (per step): reduce partials + bias + leaky-integrate + retanh.
// Grid = 160 blocks x 64 threads (lane = batch). rates written line-packed
// via padded LDS transpose tile.
// ---------------------------------------------------------------------------
__global__ __launch_bounds__(64) void rnn_fin(
    const float* __restrict__ part, const float* __restrict__ brec,
    float* __restrict__ xT, float* __restrict__ rdst,
    float* __restrict__ rates, int t)
{
  __shared__ float lds[16][65];
  int hg = blockIdx.x;
  int lane = threadIdx.x;
  int h0 = hg * 16;
  int a  = (hg < 128) ? (hg >> 5) : ((hg - 128) >> 3);
  int nE = (a == 0 || a == 3) ? 8 : 12;
  int nch = nE + 1 + (a == 0 ? 1 : 0);   // 10 / 13 / 13 / 9

  float acc[16];
  #pragma unroll
  for (int h = 0; h < 16; ++h) acc[h] = 0.f;

  const float* pb = part + ((size_t)hg * MAXC * 16) * 64 + lane;
  for (int cc = 0; cc < nch; ++cc) {
    #pragma unroll
    for (int h = 0; h < 16; ++h)
      acc[h] += pb[(cc * 16 + h) * 64];
  }

  #pragma unroll
  for (int h = 0; h < 16; ++h) {
    float pre = acc[h] + brec[h0 + h];
    size_t xi = (size_t)(h0 + h) * 64 + lane;
    float x = xT[xi];
    x = 0.8f * x + 0.2f * pre;          // ALPHA_X = 0.2
    xT[xi] = x;
    float rr = tanhf(fmaxf(x, 0.f));
    rdst[xi] = rr;
    lds[h][lane] = rr;
  }
  __syncthreads();

  // line-packed rates write: 16 lanes cover one 64 B h-segment of a b-row
  float* rt = rates + (size_t)t * (Bn * Hn) + h0;
  int hh = lane & 15;
  int q  = lane >> 4;
  #pragma unroll
  for (int j = 0; j < 16; ++j) {
    int b = j * 4 + q;
    rt[(size_t)b * Hn + hh] = lds[hh][b];
  }
}

// ---------------------------------------------------------------------------
extern "C" void kernel_launch(void* const* d_in, const int* in_sizes, int n_in,
                              void* d_out, int out_size, void* d_ws, size_t ws_size,
                              hipStream_t stream) {
  const float* inputs = (const float*)d_in[0];   // [T, 64, 128]
  const float* Wrec   = (const float*)d_in[1];   // [2560, 2560]
  const float* brec   = (const float*)d_in[2];   // [2560]
  const float* Win    = (const float*)d_in[3];   // [2560, 128]
  int T = in_sizes[0] / (Bn * INW);              // 500

  float* ws = (float*)d_ws;
  size_t off = 0;
  float* WT   = ws + off; off += (size_t)Hn * Hn;          // 6.55M
  float* WinT = ws + off; off += (size_t)INW * Hn;         // 0.33M
  float* xT   = ws + off; off += (size_t)Hn * Bn;
  float* rA   = ws + off; off += (size_t)Hn * Bn;
  float* rB   = ws + off; off += (size_t)Hn * Bn;
  float* part = ws + off; off += (size_t)HGn * MAXC * 16 * 64;   // 2.13M
  float* inpT = ws + off;
  size_t needInpT = (off + (size_t)T * INW * Bn) * sizeof(float);
  int useInpT = (ws_size >= needInpT) ? 1 : 0;

  // x0 = 0, r0 = retanh(0) = 0  (ws poisoned 0xAA each call)
  hipMemsetAsync(xT, 0, (size_t)Hn * Bn * sizeof(float), stream);
  hipMemsetAsync(rA, 0, (size_t)Hn * Bn * sizeof(float), stream);

  build_wrecT<<<dim3(40, 40), dim3(64, 16), 0, stream>>>(Wrec, WT);
  build_winT<<<dim3(40, 2), dim3(64, 16), 0, stream>>>(Win, WinT);
  if (useInpT) build_inpT<<<T, 256, 0, stream>>>(inputs, inpT);

  float* rates = (float*)d_out;
  for (int t = 0; t < T; ++t) {
    const float* rs = (t & 1) ? rB : rA;
    float*       rd = (t & 1) ? rA : rB;
    rnn_mm<<<1800, 64, 0, stream>>>(WT, WinT, inpT, inputs, rs, part, t, useInpT);
    rnn_fin<<<160, 64, 0, stream>>>(part, brec, xT, rd, rates, t);
  }
}